// Round 22
// baseline (48.870 us; speedup 1.0000x reference)
//
#include <hip/hip_runtime.h>

#define L    2048
#define HALF 1024
#define NM   10
#define NG   20
#define NF   30

#define NCC2 2000   // coarse blocks = (m, i2, i3-pair)
#define NFB2 900    // fine blocks   = (j2, j3-pair, ec)
#define NBF  106    // ceil(27000/256) k_ffin blocks

// ---- float workspace layout (float indices) ----
#define OFF_SC   0                        // float2 sc[1024] = {sin^2, sin*td}
#define OFF_TAB  2048                     // float2 tab[NM*HALF] = {lc, ls}
#define OFF_G20  (2048 + 2*NM*HALF)       // 22528: grid20[20]
#define OFF_R20  (OFF_G20 + 20)           // -1/grid20 [20]
#define OFF_CN   (OFF_R20 + 20)           // {cn1, cn2, cn3, (float)m} [4]
#define OFF_DWS  (OFF_CN + 4)             // 22572 floats -> byte 90288 (%8==0)

#define EXP2F(x) __builtin_amdgcn_exp2f(x)
#define LOG2F(x) __builtin_amdgcn_logf(x)

typedef float f32x2 __attribute__((ext_vector_type(2)));

__device__ __forceinline__ f32x2 pk_mul(f32x2 a, f32x2 b) { return a * b; }
__device__ __forceinline__ f32x2 pk_fma(f32x2 a, f32x2 b, f32x2 c) {
  return __builtin_elementwise_fma(a, b, c);
}
__device__ __forceinline__ f32x2 pk_exp2(f32x2 v) {
  f32x2 e; e.x = EXP2F(v.x); e.y = EXP2F(v.y); return e;
}

// ---- wave64 sum via DPP (VALU-only, no LDS): result valid in LANE 63 ----
#define DPP_ADD(x, ctrl, rmask)                                              \
  x += __builtin_bit_cast(float, __builtin_amdgcn_update_dpp(                \
         0, __builtin_bit_cast(int, x), ctrl, rmask, 0xf, true))
__device__ __forceinline__ float wave_sum63(float x) {
  DPP_ADD(x, 0x111, 0xf);   // row_shr:1
  DPP_ADD(x, 0x112, 0xf);   // row_shr:2
  DPP_ADD(x, 0x114, 0xf);   // row_shr:4
  DPP_ADD(x, 0x118, 0xf);   // row_shr:8  -> lane15 of each row = row sum
  DPP_ADD(x, 0x142, 0xa);   // row_bcast:15 -> rows 1,3
  DPP_ADD(x, 0x143, 0xc);   // row_bcast:31 -> rows 2,3; lane 63 = total
  return x;
}

__device__ __forceinline__ float grid20(int i) {
  double e = -1.0 + 2.0 * (double)i / 19.0;
  return (float)exp2(e * 3.3219280948873623478703194294894);
}
__device__ __forceinline__ float finev(float c, int j) {
  return (float)((double)c * 0.8 + (double)j * ((double)c * 0.4 / 29.0));
}
__device__ __forceinline__ double mse_from(double sgg2, double sgt, double sum_tt) {
  double S = sgg2; if (S < 0.0) S = 0.0;
  double d = sqrt(S / (double)(L - 1)) + 1e-6;
  return (S / (d * d) - 2.0 * sgt / d + sum_tt) / (double)L;
}
__device__ __forceinline__ void vt_wave_reduce(double& v, int& t) {
  for (int o = 32; o > 0; o >>= 1) {
    double ov = __shfl_down(v, o);
    int ot = __shfl_down(t, o);
    if (ov < v || (ov == v && ot < t)) { v = ov; t = ot; }
  }
}
__device__ __forceinline__ void vt_block_merge(double& v, int& t, double* sv, int* st) {
  int lane = threadIdx.x & 63, w = threadIdx.x >> 6;
  vt_wave_reduce(v, t);
  if (lane == 0) { sv[w] = v; st[w] = t; }
  __syncthreads();
  if (threadIdx.x == 0) {
    for (int k = 1; k < 4; k++)
      if (sv[k] < v || (sv[k] == v && st[k] < t)) { v = sv[k]; t = st[k]; }
  }
}

// ---------------- K1: setup (block 0) + tables (blocks 1..40, parallel) ----
__global__ __launch_bounds__(256) void k_init(const float* __restrict__ x,
                                              const int* __restrict__ freqp,
                                              float* __restrict__ fws,
                                              double* __restrict__ dstt) {
  if (blockIdx.x == 0) {
    int tid = threadIdx.x;
    int lane = tid & 63, w = tid >> 6;
    __shared__ double sh[8];
    __shared__ double s_mean, s_d;

    double sx = 0.0, sxx = 0.0;
    for (int l = tid; l < L; l += 256) {
      double v = (double)x[l];
      sx += v; sxx += v * v;
    }
    for (int o = 32; o > 0; o >>= 1) { sx += __shfl_down(sx, o); sxx += __shfl_down(sxx, o); }
    if (lane == 0) { sh[w] = sx; sh[4 + w] = sxx; }
    __syncthreads();
    if (tid == 0) {
      sx = sh[0] + sh[1] + sh[2] + sh[3];
      sxx = sh[4] + sh[5] + sh[6] + sh[7];
      double mean = sx / (double)L;
      double S = sxx - sx * sx / (double)L; if (S < 0.0) S = 0.0;
      s_mean = mean; s_d = sqrt(S / (double)(L - 1)) + 1e-6;
    }
    __syncthreads();
    double mean = s_mean, d = s_d;
    double freq = (double)freqp[0];

    double stt = 0.0;
    for (int l = tid; l < HALF; l += 256) {
      float tva = (float)(((double)x[l] - mean) / d);
      float tvb = (float)(((double)x[L - 1 - l] - mean) / d);
      float tdv = tva - tvb;
      double t = -1.0 + 2.0 * (double)l / 2047.0;
      float spv = (float)sin(6.2831853071795864769 * freq * t);
      float2 scv; scv.x = spv * spv; scv.y = spv * tdv;
      reinterpret_cast<float2*>(fws + OFF_SC)[l] = scv;
      stt += (double)tva * (double)tva + (double)tvb * (double)tvb;
    }
    for (int o = 32; o > 0; o >>= 1) { stt += __shfl_down(stt, o); }
    __syncthreads();
    if (lane == 0) { sh[w] = stt; }
    __syncthreads();
    if (tid == 0) { dstt[0] = sh[0] + sh[1] + sh[2] + sh[3]; }
  } else {
    int idx = (blockIdx.x - 1) * 256 + threadIdx.x;   // [0, NM*HALF)
    if (idx < NM * HALF) {
      int m = idx / HALF, l = idx % HALF;
      double freq = (double)freqp[0];
      double t = -1.0 + 2.0 * (double)l / 2047.0;
      double theta = 6.2831853071795864769 * freq * t * 0.25;   // phi/4
      double sv, cv;
      sincos((double)(m + 1) * theta, &sv, &cv);
      float2 v;
      v.x = fmaxf(LOG2F(fabsf((float)cv)), -1.0e4f);
      v.y = fmaxf(LOG2F(fabsf((float)sv)), -1.0e4f);
      reinterpret_cast<float2*>(fws + OFF_TAB)[m * HALF + l] = v;
    }
    if (blockIdx.x == 1 && threadIdx.x < NG) {
      float g = grid20(threadIdx.x);
      fws[OFF_G20 + threadIdx.x] = g;
      fws[OFF_R20 + threadIdx.x] = -1.0f / g;
    }
  }
}

// ---------------- K2: coarse scan — packed pairs, DPP, forced 8 waves/SIMD -
__global__ __launch_bounds__(256, 8) void k_coarse(const float* __restrict__ fws,
                                                   const double* __restrict__ dstt,
                                                   double* __restrict__ bv,
                                                   int* __restrict__ bt) {
  __shared__ float4 row_ls[512];   // 8 KB
  __shared__ float4 row_sc[512];   // 8 KB
  __shared__ float2 cells[40];
  __shared__ int cellt[40];
  int tid = threadIdx.x, lane = tid & 63, w = tid >> 6;
  int b = blockIdx.x;
  int m = b / 200;
  int rem = b % 200;
  int i2 = rem / 10;
  int p3 = rem % 10;
  int i3A = 2 * p3;
  float n2 = fws[OFF_G20 + i2];
  float n3A = fws[OFF_G20 + i3A];
  float n3B = fws[OFF_G20 + i3A + 1];

  const float2* tab = reinterpret_cast<const float2*>(fws + OFF_TAB) + m * HALF;
  const float2* sc = reinterpret_cast<const float2*>(fws + OFF_SC);
#pragma unroll
  for (int k = 0; k < 2; k++) {
    int q = tid + k * 256;          // pair index [0,512)
    int e0 = 2 * q, e1 = e0 + 1;
    float2 tb0 = tab[e0], tb1 = tab[e1];
    float2 s0 = sc[e0], s1 = sc[e1];
    float a20 = EXP2F(n2 * tb0.x), a21 = EXP2F(n2 * tb1.x);
    float4 ls;
    ls.x = LOG2F(a20 + EXP2F(n3A * tb0.y));
    ls.y = LOG2F(a21 + EXP2F(n3A * tb1.y));
    ls.z = LOG2F(a20 + EXP2F(n3B * tb0.y));
    ls.w = LOG2F(a21 + EXP2F(n3B * tb1.y));
    row_ls[q] = ls;
    row_sc[q] = make_float4(s0.x, s1.x, s0.y, s1.y);
  }
  __syncthreads();

#pragma unroll
  for (int pass = 0; pass < 3; ++pass) {
    const bool two = (pass < 2);
    int i1a = w * 5 + pass * 2;
    float r0s = fws[OFF_R20 + i1a];
    float r1s = two ? fws[OFF_R20 + i1a + 1] : 0.0f;
    f32x2 r0 = {r0s, r0s}, r1 = {r1s, r1s};
    f32x2 z = {0.0f, 0.0f};
    f32x2 aA0 = z, tA0 = z, aB0 = z, tB0 = z;
    f32x2 aA1 = z, tA1 = z, aB1 = z, tB1 = z;
#pragma unroll 4
    for (int it = 0; it < 8; ++it) {
      int q = lane + it * 64;
      float4 ls4 = row_ls[q];
      float4 sc4 = row_sc[q];
      f32x2 lsA = {ls4.x, ls4.y}, lsB = {ls4.z, ls4.w};
      f32x2 sx = {sc4.x, sc4.y}, sy = {sc4.z, sc4.w};
      f32x2 e, e2;
      e = pk_exp2(pk_mul(r0, lsA)); e2 = pk_mul(e, e);
      aA0 = pk_fma(e2, sx, aA0); tA0 = pk_fma(e, sy, tA0);
      e = pk_exp2(pk_mul(r0, lsB)); e2 = pk_mul(e, e);
      aB0 = pk_fma(e2, sx, aB0); tB0 = pk_fma(e, sy, tB0);
      if (two) {
        e = pk_exp2(pk_mul(r1, lsA)); e2 = pk_mul(e, e);
        aA1 = pk_fma(e2, sx, aA1); tA1 = pk_fma(e, sy, tA1);
        e = pk_exp2(pk_mul(r1, lsB)); e2 = pk_mul(e, e);
        aB1 = pk_fma(e2, sx, aB1); tB1 = pk_fma(e, sy, tB1);
      }
    }
    float aA0s = wave_sum63(aA0.x + aA0.y);
    float tA0s = wave_sum63(tA0.x + tA0.y);
    float aB0s = wave_sum63(aB0.x + aB0.y);
    float tB0s = wave_sum63(tB0.x + tB0.y);
    float aA1s = 0.0f, tA1s = 0.0f, aB1s = 0.0f, tB1s = 0.0f;
    if (two) {
      aA1s = wave_sum63(aA1.x + aA1.y);
      tA1s = wave_sum63(tA1.x + tA1.y);
      aB1s = wave_sum63(aB1.x + aB1.y);
      tB1s = wave_sum63(tB1.x + tB1.y);
    }
    if (lane == 63) {
      int t0 = ((m * NG + i1a) * NG + i2) * NG + i3A;   // ref flat index
      int s0 = w * 10 + pass * 4;
      cells[s0]     = make_float2(aA0s, tA0s); cellt[s0]     = t0;
      cells[s0 + 1] = make_float2(aB0s, tB0s); cellt[s0 + 1] = t0 + 1;
      if (two) {
        cells[s0 + 2] = make_float2(aA1s, tA1s); cellt[s0 + 2] = t0 + NG * NG;
        cells[s0 + 3] = make_float2(aB1s, tB1s); cellt[s0 + 3] = t0 + NG * NG + 1;
      }
    }
  }
  __syncthreads();

  if (w == 0) {
    double v = 1e300; int t = 0x7fffffff;
    if (lane < 40) {
      float2 p = cells[lane];
      v = mse_from(2.0 * (double)p.x, (double)p.y, dstt[0]);
      t = cellt[lane];
    }
    vt_wave_reduce(v, t);
    if (lane == 0) { bv[b] = v; bt[b] = t; }
  }
}

// ---------------- K3: coarse argmin once -> {cn1,cn2,cn3,m} ----------------
__global__ __launch_bounds__(256) void k_cmin(const double* __restrict__ bvc,
                                              const int* __restrict__ btc,
                                              float* __restrict__ fws) {
  __shared__ double sv[4];
  __shared__ int st[4];
  double v = 1e300; int t = 0x7fffffff;
  for (int i = threadIdx.x; i < NCC2; i += 256) {
    double ov = bvc[i]; int ot = btc[i];
    if (ov < v || (ov == v && ot < t)) { v = ov; t = ot; }
  }
  vt_block_merge(v, t, sv, st);
  if (threadIdx.x == 0) {
    int ci = t;
    int m  = ci / (NG * NG * NG);
    int rr = ci % (NG * NG * NG);
    fws[OFF_CN + 0] = grid20(rr / (NG * NG));
    fws[OFF_CN + 1] = grid20((rr / NG) % NG);
    fws[OFF_CN + 2] = grid20(rr % NG);
    fws[OFF_CN + 3] = (float)m;
  }
}

// ---------------- K4: fine scan — ec-split, DPP, forced 8 waves/SIMD -------
__global__ __launch_bounds__(256, 8) void k_fine(const float* __restrict__ fws,
                                                 float2* __restrict__ partf) {
  __shared__ float4 row_ls[256];   // 4 KB
  __shared__ float4 row_sc[256];   // 4 KB
  int tid = threadIdx.x, lane = tid & 63, w = tid >> 6;
  float cn1 = fws[OFF_CN + 0];
  float cn2 = fws[OFF_CN + 1];
  float cn3 = fws[OFF_CN + 2];
  int m = (int)fws[OFF_CN + 3];

  int b = blockIdx.x;
  int cp = b >> 1, ec = b & 1;
  int j2 = cp / 15;
  int p3 = cp % 15;
  int j3A = 2 * p3;
  float n2 = finev(cn2, j2);
  float n3A = finev(cn3, j3A);
  float n3B = finev(cn3, j3A + 1);

  const float2* tab = reinterpret_cast<const float2*>(fws + OFF_TAB) + m * HALF;
  const float2* sc = reinterpret_cast<const float2*>(fws + OFF_SC);
  {
    int q = tid;                       // local pair [0,256)
    int gq = ec * 256 + q;             // global pair
    int e0 = 2 * gq, e1 = e0 + 1;
    float2 tb0 = tab[e0], tb1 = tab[e1];
    float2 s0 = sc[e0], s1 = sc[e1];
    float a20 = EXP2F(n2 * tb0.x), a21 = EXP2F(n2 * tb1.x);
    float4 ls;
    ls.x = LOG2F(a20 + EXP2F(n3A * tb0.y));
    ls.y = LOG2F(a21 + EXP2F(n3A * tb1.y));
    ls.z = LOG2F(a20 + EXP2F(n3B * tb0.y));
    ls.w = LOG2F(a21 + EXP2F(n3B * tb1.y));
    row_ls[q] = ls;
    row_sc[q] = make_float4(s0.x, s1.x, s0.y, s1.y);
  }
  __syncthreads();

  int npairs = (w < 3) ? 4 : 3;   // j1 counts 8,8,8,6
  for (int pp = 0; pp < npairs; ++pp) {
    int j1a = w * 8 + pp * 2;
    float r0s = -1.0f / finev(cn1, j1a);
    float r1s = -1.0f / finev(cn1, j1a + 1);
    f32x2 r0 = {r0s, r0s}, r1 = {r1s, r1s};
    f32x2 z = {0.0f, 0.0f};
    f32x2 aA0 = z, tA0 = z, aB0 = z, tB0 = z;
    f32x2 aA1 = z, tA1 = z, aB1 = z, tB1 = z;
#pragma unroll 4
    for (int it = 0; it < 4; ++it) {
      int q = lane + it * 64;
      float4 ls4 = row_ls[q];
      float4 sc4 = row_sc[q];
      f32x2 lsA = {ls4.x, ls4.y}, lsB = {ls4.z, ls4.w};
      f32x2 sx = {sc4.x, sc4.y}, sy = {sc4.z, sc4.w};
      f32x2 e, e2;
      e = pk_exp2(pk_mul(r0, lsA)); e2 = pk_mul(e, e);
      aA0 = pk_fma(e2, sx, aA0); tA0 = pk_fma(e, sy, tA0);
      e = pk_exp2(pk_mul(r0, lsB)); e2 = pk_mul(e, e);
      aB0 = pk_fma(e2, sx, aB0); tB0 = pk_fma(e, sy, tB0);
      e = pk_exp2(pk_mul(r1, lsA)); e2 = pk_mul(e, e);
      aA1 = pk_fma(e2, sx, aA1); tA1 = pk_fma(e, sy, tA1);
      e = pk_exp2(pk_mul(r1, lsB)); e2 = pk_mul(e, e);
      aB1 = pk_fma(e2, sx, aB1); tB1 = pk_fma(e, sy, tB1);
    }
    float aA0s = wave_sum63(aA0.x + aA0.y);
    float tA0s = wave_sum63(tA0.x + tA0.y);
    float aB0s = wave_sum63(aB0.x + aB0.y);
    float tB0s = wave_sum63(tB0.x + tB0.y);
    float aA1s = wave_sum63(aA1.x + aA1.y);
    float tA1s = wave_sum63(tA1.x + tA1.y);
    float aB1s = wave_sum63(aB1.x + aB1.y);
    float tB1s = wave_sum63(tB1.x + tB1.y);
    if (lane == 63) {
      int t0 = (j1a * NF + j2) * NF + j3A;   // fine flat index
      partf[2 * t0 + ec]       = make_float2(aA0s, tA0s);
      partf[2 * (t0 + 1) + ec] = make_float2(aB0s, tB0s);
      int t1 = t0 + NF * NF;
      partf[2 * t1 + ec]       = make_float2(aA1s, tA1s);
      partf[2 * (t1 + 1) + ec] = make_float2(aB1s, tB1s);
    }
  }
}

// ---------------- K5: fine finalize (combine halves, f64) + argmin st.1 ----
__global__ __launch_bounds__(256) void k_ffin(const float2* __restrict__ partf,
                                              const double* __restrict__ dstt,
                                              double* __restrict__ pv,
                                              int* __restrict__ pi) {
  int t = blockIdx.x * 256 + threadIdx.x;
  double best = 1e300; int bi = 0x7fffffff;
  if (t < NF * NF * NF) {
    float2 p0 = partf[2 * t];
    float2 p1 = partf[2 * t + 1];
    double sgg = (double)p0.x + (double)p1.x;
    double sgt = (double)p0.y + (double)p1.y;
    best = mse_from(2.0 * sgg, sgt, dstt[0]);
    bi = t;
  }
  __shared__ double sv[4];
  __shared__ int st[4];
  vt_block_merge(best, bi, sv, st);
  if (threadIdx.x == 0) { pv[blockIdx.x] = best; pi[blockIdx.x] = bi; }
}

// ---------------- K6: final fine argmin + emit -----------------------------
__global__ __launch_bounds__(256) void k_out(const float* __restrict__ fws,
                                             const double* __restrict__ pvf,
                                             const int* __restrict__ pif,
                                             float* __restrict__ out) {
  __shared__ double sv[4];
  __shared__ int st[4];
  double v = 1e300; int t = 0x7fffffff;
  for (int i = threadIdx.x; i < NBF; i += 256) {
    double ov = pvf[i]; int ot = pif[i];
    if (ov < v || (ov == v && ot < t)) { v = ov; t = ot; }
  }
  vt_block_merge(v, t, sv, st);
  if (threadIdx.x == 0) {
    float cn1 = fws[OFF_CN + 0];
    float cn2 = fws[OFF_CN + 1];
    float cn3 = fws[OFF_CN + 2];
    int m = (int)fws[OFF_CN + 3];
    int fi = t;
    int f1 = fi / (NF * NF);
    int fc = fi % (NF * NF);
    out[0] = (float)(m + 1);
    out[1] = finev(cn1, f1);
    out[2] = finev(cn2, fc / NF);
    out[3] = finev(cn3, fc % NF);
  }
}

extern "C" void kernel_launch(void* const* d_in, const int* in_sizes, int n_in,
                              void* d_out, int out_size, void* d_ws, size_t ws_size,
                              hipStream_t stream) {
  const float* x = (const float*)d_in[0];
  const int* freqp = (const int*)d_in[1];
  float* out = (float*)d_out;
  float* fws = (float*)d_ws;

  double* D0  = (double*)(fws + OFF_DWS);   // byte 90288, 8-aligned
  double* dstt = D0;                        // [1]
  double* bvc = D0 + 1;                     // NCC2 doubles
  double* pvf = bvc + NCC2;                 // NBF doubles
  int* btc = (int*)(pvf + NBF);             // NCC2 ints
  int* pif = btc + NCC2;                    // NBF ints
  float2* partf = (float2*)(pif + NBF + 1); // 27000*2 float2 (8B-aligned)

  hipLaunchKernelGGL(k_init,   dim3(41),   dim3(256), 0, stream, x, freqp, fws, dstt);
  hipLaunchKernelGGL(k_coarse, dim3(NCC2), dim3(256), 0, stream, fws, dstt, bvc, btc);
  hipLaunchKernelGGL(k_cmin,   dim3(1),    dim3(256), 0, stream, bvc, btc, fws);
  hipLaunchKernelGGL(k_fine,   dim3(NFB2), dim3(256), 0, stream, fws, partf);
  hipLaunchKernelGGL(k_ffin,   dim3(NBF),  dim3(256), 0, stream, partf, dstt, pvf, pif);
  hipLaunchKernelGGL(k_out,    dim3(1),    dim3(256), 0, stream, fws, pvf, pif, out);
}

// Round 23
// 46.931 us; speedup vs baseline: 1.0413x; 1.0413x over previous
//
#include <hip/hip_runtime.h>

#define L    2048
#define HALF 1024
#define NM   10
#define NG   20
#define NF   30

#define NCC2 2000   // coarse blocks = (m, i2, i3-pair)
#define NFB2 900    // fine blocks   = (j2, j3-pair, ec)
#define NBF  106    // ceil(27000/256) k_ffin blocks

// ---- float workspace layout (float indices) ----
#define OFF_SC   0                        // float2 sc[1024] = {sin^2, sin*td}
#define OFF_TAB  2048                     // float2 tab[NM*HALF] = {lc, ls}
#define OFF_G20  (2048 + 2*NM*HALF)       // 22528: grid20[20]
#define OFF_R20  (OFF_G20 + 20)           // -1/grid20 [20]
#define OFF_CN   (OFF_R20 + 20)           // {cn1, cn2, cn3, (float)m} [4]
#define OFF_DWS  (OFF_CN + 4)             // 22572 floats -> byte 90288 (%8==0)

#define EXP2F(x) __builtin_amdgcn_exp2f(x)
#define LOG2F(x) __builtin_amdgcn_logf(x)

typedef float f32x2 __attribute__((ext_vector_type(2)));

__device__ __forceinline__ f32x2 pk_mul(f32x2 a, f32x2 b) { return a * b; }
__device__ __forceinline__ f32x2 pk_fma(f32x2 a, f32x2 b, f32x2 c) {
  return __builtin_elementwise_fma(a, b, c);
}
__device__ __forceinline__ f32x2 pk_exp2(f32x2 v) {
  f32x2 e; e.x = EXP2F(v.x); e.y = EXP2F(v.y); return e;
}

// ---- wave64 sum via DPP (VALU-only, no LDS): result valid in LANE 63 ----
#define DPP_ADD(x, ctrl, rmask)                                              \
  x += __builtin_bit_cast(float, __builtin_amdgcn_update_dpp(                \
         0, __builtin_bit_cast(int, x), ctrl, rmask, 0xf, true))
__device__ __forceinline__ float wave_sum63(float x) {
  DPP_ADD(x, 0x111, 0xf);   // row_shr:1
  DPP_ADD(x, 0x112, 0xf);   // row_shr:2
  DPP_ADD(x, 0x114, 0xf);   // row_shr:4
  DPP_ADD(x, 0x118, 0xf);   // row_shr:8  -> lane15 of each row = row sum
  DPP_ADD(x, 0x142, 0xa);   // row_bcast:15 -> rows 1,3
  DPP_ADD(x, 0x143, 0xc);   // row_bcast:31 -> rows 2,3; lane 63 = total
  return x;
}

__device__ __forceinline__ float grid20(int i) {
  double e = -1.0 + 2.0 * (double)i / 19.0;
  return (float)exp2(e * 3.3219280948873623478703194294894);
}
__device__ __forceinline__ float finev(float c, int j) {
  return (float)((double)c * 0.8 + (double)j * ((double)c * 0.4 / 29.0));
}
__device__ __forceinline__ double mse_from(double sgg2, double sgt, double sum_tt) {
  double S = sgg2; if (S < 0.0) S = 0.0;
  double d = sqrt(S / (double)(L - 1)) + 1e-6;
  return (S / (d * d) - 2.0 * sgt / d + sum_tt) / (double)L;
}
__device__ __forceinline__ void vt_wave_reduce(double& v, int& t) {
  for (int o = 32; o > 0; o >>= 1) {
    double ov = __shfl_down(v, o);
    int ot = __shfl_down(t, o);
    if (ov < v || (ov == v && ot < t)) { v = ov; t = ot; }
  }
}
__device__ __forceinline__ void vt_block_merge(double& v, int& t, double* sv, int* st) {
  int lane = threadIdx.x & 63, w = threadIdx.x >> 6;
  vt_wave_reduce(v, t);
  if (lane == 0) { sv[w] = v; st[w] = t; }
  __syncthreads();
  if (threadIdx.x == 0) {
    for (int k = 1; k < 4; k++)
      if (sv[k] < v || (sv[k] == v && st[k] < t)) { v = sv[k]; t = st[k]; }
  }
}

// ---------------- K1: setup (block 0) + tables (blocks 1..40, parallel) ----
__global__ __launch_bounds__(256) void k_init(const float* __restrict__ x,
                                              const int* __restrict__ freqp,
                                              float* __restrict__ fws,
                                              double* __restrict__ dstt) {
  if (blockIdx.x == 0) {
    int tid = threadIdx.x;
    int lane = tid & 63, w = tid >> 6;
    __shared__ double sh[8];
    __shared__ double s_mean, s_d;

    double sx = 0.0, sxx = 0.0;
    for (int l = tid; l < L; l += 256) {
      double v = (double)x[l];
      sx += v; sxx += v * v;
    }
    for (int o = 32; o > 0; o >>= 1) { sx += __shfl_down(sx, o); sxx += __shfl_down(sxx, o); }
    if (lane == 0) { sh[w] = sx; sh[4 + w] = sxx; }
    __syncthreads();
    if (tid == 0) {
      sx = sh[0] + sh[1] + sh[2] + sh[3];
      sxx = sh[4] + sh[5] + sh[6] + sh[7];
      double mean = sx / (double)L;
      double S = sxx - sx * sx / (double)L; if (S < 0.0) S = 0.0;
      s_mean = mean; s_d = sqrt(S / (double)(L - 1)) + 1e-6;
    }
    __syncthreads();
    double mean = s_mean, d = s_d;
    double freq = (double)freqp[0];

    double stt = 0.0;
    for (int l = tid; l < HALF; l += 256) {
      float tva = (float)(((double)x[l] - mean) / d);
      float tvb = (float)(((double)x[L - 1 - l] - mean) / d);
      float tdv = tva - tvb;
      double t = -1.0 + 2.0 * (double)l / 2047.0;
      float spv = (float)sin(6.2831853071795864769 * freq * t);
      float2 scv; scv.x = spv * spv; scv.y = spv * tdv;
      reinterpret_cast<float2*>(fws + OFF_SC)[l] = scv;
      stt += (double)tva * (double)tva + (double)tvb * (double)tvb;
    }
    for (int o = 32; o > 0; o >>= 1) { stt += __shfl_down(stt, o); }
    __syncthreads();
    if (lane == 0) { sh[w] = stt; }
    __syncthreads();
    if (tid == 0) { dstt[0] = sh[0] + sh[1] + sh[2] + sh[3]; }
  } else {
    int idx = (blockIdx.x - 1) * 256 + threadIdx.x;   // [0, NM*HALF)
    if (idx < NM * HALF) {
      int m = idx / HALF, l = idx % HALF;
      double freq = (double)freqp[0];
      double t = -1.0 + 2.0 * (double)l / 2047.0;
      double theta = 6.2831853071795864769 * freq * t * 0.25;   // phi/4
      double sv, cv;
      sincos((double)(m + 1) * theta, &sv, &cv);
      float2 v;
      v.x = fmaxf(LOG2F(fabsf((float)cv)), -1.0e4f);
      v.y = fmaxf(LOG2F(fabsf((float)sv)), -1.0e4f);
      reinterpret_cast<float2*>(fws + OFF_TAB)[m * HALF + l] = v;
    }
    if (blockIdx.x == 1 && threadIdx.x < NG) {
      float g = grid20(threadIdx.x);
      fws[OFF_G20 + threadIdx.x] = g;
      fws[OFF_R20 + threadIdx.x] = -1.0f / g;
    }
  }
}

// ---------------- K2: coarse scan — SINGLE fused element loop --------------
// wave w owns i1 in [5w, 5w+5); 20 named f32x2 accumulators; one LDS
// read-pair feeds all 10 (i1,combo) evals -> 16 ds_reads/wave, 20 dep chains.
__global__ __launch_bounds__(256) void k_coarse(const float* __restrict__ fws,
                                                const double* __restrict__ dstt,
                                                double* __restrict__ bv,
                                                int* __restrict__ bt) {
  __shared__ float4 row_ls[512];   // 8 KB
  __shared__ float4 row_sc[512];   // 8 KB
  __shared__ float2 cells[40];
  __shared__ int cellt[40];
  int tid = threadIdx.x, lane = tid & 63, w = tid >> 6;
  int b = blockIdx.x;
  int m = b / 200;
  int rem = b % 200;
  int i2 = rem / 10;
  int p3 = rem % 10;
  int i3A = 2 * p3;
  float n2 = fws[OFF_G20 + i2];
  float n3A = fws[OFF_G20 + i3A];
  float n3B = fws[OFF_G20 + i3A + 1];

  const float2* tab = reinterpret_cast<const float2*>(fws + OFF_TAB) + m * HALF;
  const float2* sc = reinterpret_cast<const float2*>(fws + OFF_SC);
#pragma unroll
  for (int k = 0; k < 2; k++) {
    int q = tid + k * 256;          // pair index [0,512)
    int e0 = 2 * q, e1 = e0 + 1;
    float2 tb0 = tab[e0], tb1 = tab[e1];
    float2 s0 = sc[e0], s1 = sc[e1];
    float a20 = EXP2F(n2 * tb0.x), a21 = EXP2F(n2 * tb1.x);
    float4 ls;
    ls.x = LOG2F(a20 + EXP2F(n3A * tb0.y));
    ls.y = LOG2F(a21 + EXP2F(n3A * tb1.y));
    ls.z = LOG2F(a20 + EXP2F(n3B * tb0.y));
    ls.w = LOG2F(a21 + EXP2F(n3B * tb1.y));
    row_ls[q] = ls;
    row_sc[q] = make_float4(s0.x, s1.x, s0.y, s1.y);
  }
  __syncthreads();

  int i1b = w * 5;
  float r0s = fws[OFF_R20 + i1b + 0];
  float r1s = fws[OFF_R20 + i1b + 1];
  float r2s = fws[OFF_R20 + i1b + 2];
  float r3s = fws[OFF_R20 + i1b + 3];
  float r4s = fws[OFF_R20 + i1b + 4];
  f32x2 r0 = {r0s, r0s}, r1 = {r1s, r1s}, r2 = {r2s, r2s};
  f32x2 r3 = {r3s, r3s}, r4 = {r4s, r4s};
  f32x2 z = {0.0f, 0.0f};
  f32x2 aA0 = z, aA1 = z, aA2 = z, aA3 = z, aA4 = z;
  f32x2 tA0 = z, tA1 = z, tA2 = z, tA3 = z, tA4 = z;
  f32x2 aB0 = z, aB1 = z, aB2 = z, aB3 = z, aB4 = z;
  f32x2 tB0 = z, tB1 = z, tB2 = z, tB3 = z, tB4 = z;

#pragma unroll 2
  for (int it = 0; it < 8; ++it) {
    int q = lane + it * 64;
    float4 ls4 = row_ls[q];
    float4 sc4 = row_sc[q];
    f32x2 lsA = {ls4.x, ls4.y}, lsB = {ls4.z, ls4.w};
    f32x2 sx = {sc4.x, sc4.y}, sy = {sc4.z, sc4.w};
#define EV(R, AA, TT, LS) do {                                     \
    f32x2 e = pk_exp2(pk_mul(R, LS));                              \
    f32x2 e2 = pk_mul(e, e);                                       \
    AA = pk_fma(e2, sx, AA); TT = pk_fma(e, sy, TT);               \
  } while (0)
    EV(r0, aA0, tA0, lsA); EV(r1, aA1, tA1, lsA); EV(r2, aA2, tA2, lsA);
    EV(r3, aA3, tA3, lsA); EV(r4, aA4, tA4, lsA);
    EV(r0, aB0, tB0, lsB); EV(r1, aB1, tB1, lsB); EV(r2, aB2, tB2, lsB);
    EV(r3, aB3, tB3, lsB); EV(r4, aB4, tB4, lsB);
#undef EV
  }

  // 20 wave reductions (DPP), results in lane 63
  float sA0 = wave_sum63(aA0.x + aA0.y), uA0 = wave_sum63(tA0.x + tA0.y);
  float sA1 = wave_sum63(aA1.x + aA1.y), uA1 = wave_sum63(tA1.x + tA1.y);
  float sA2 = wave_sum63(aA2.x + aA2.y), uA2 = wave_sum63(tA2.x + tA2.y);
  float sA3 = wave_sum63(aA3.x + aA3.y), uA3 = wave_sum63(tA3.x + tA3.y);
  float sA4 = wave_sum63(aA4.x + aA4.y), uA4 = wave_sum63(tA4.x + tA4.y);
  float sB0 = wave_sum63(aB0.x + aB0.y), uB0 = wave_sum63(tB0.x + tB0.y);
  float sB1 = wave_sum63(aB1.x + aB1.y), uB1 = wave_sum63(tB1.x + tB1.y);
  float sB2 = wave_sum63(aB2.x + aB2.y), uB2 = wave_sum63(tB2.x + tB2.y);
  float sB3 = wave_sum63(aB3.x + aB3.y), uB3 = wave_sum63(tB3.x + tB3.y);
  float sB4 = wave_sum63(aB4.x + aB4.y), uB4 = wave_sum63(tB4.x + tB4.y);

  if (lane == 63) {
    int t0 = ((m * NG + i1b) * NG + i2) * NG + i3A;   // q=0, combo A
    int s0 = w * 10;
    cells[s0 + 0] = make_float2(sA0, uA0); cellt[s0 + 0] = t0;
    cells[s0 + 1] = make_float2(sB0, uB0); cellt[s0 + 1] = t0 + 1;
    cells[s0 + 2] = make_float2(sA1, uA1); cellt[s0 + 2] = t0 + 1 * NG * NG;
    cells[s0 + 3] = make_float2(sB1, uB1); cellt[s0 + 3] = t0 + 1 * NG * NG + 1;
    cells[s0 + 4] = make_float2(sA2, uA2); cellt[s0 + 4] = t0 + 2 * NG * NG;
    cells[s0 + 5] = make_float2(sB2, uB2); cellt[s0 + 5] = t0 + 2 * NG * NG + 1;
    cells[s0 + 6] = make_float2(sA3, uA3); cellt[s0 + 6] = t0 + 3 * NG * NG;
    cells[s0 + 7] = make_float2(sB3, uB3); cellt[s0 + 7] = t0 + 3 * NG * NG + 1;
    cells[s0 + 8] = make_float2(sA4, uA4); cellt[s0 + 8] = t0 + 4 * NG * NG;
    cells[s0 + 9] = make_float2(sB4, uB4); cellt[s0 + 9] = t0 + 4 * NG * NG + 1;
  }
  __syncthreads();

  if (w == 0) {
    double v = 1e300; int t = 0x7fffffff;
    if (lane < 40) {
      float2 p = cells[lane];
      v = mse_from(2.0 * (double)p.x, (double)p.y, dstt[0]);
      t = cellt[lane];
    }
    vt_wave_reduce(v, t);
    if (lane == 0) { bv[b] = v; bt[b] = t; }
  }
}

// ---------------- K3: coarse argmin once -> {cn1,cn2,cn3,m} ----------------
__global__ __launch_bounds__(256) void k_cmin(const double* __restrict__ bvc,
                                              const int* __restrict__ btc,
                                              float* __restrict__ fws) {
  __shared__ double sv[4];
  __shared__ int st[4];
  double v = 1e300; int t = 0x7fffffff;
  for (int i = threadIdx.x; i < NCC2; i += 256) {
    double ov = bvc[i]; int ot = btc[i];
    if (ov < v || (ov == v && ot < t)) { v = ov; t = ot; }
  }
  vt_block_merge(v, t, sv, st);
  if (threadIdx.x == 0) {
    int ci = t;
    int m  = ci / (NG * NG * NG);
    int rr = ci % (NG * NG * NG);
    fws[OFF_CN + 0] = grid20(rr / (NG * NG));
    fws[OFF_CN + 1] = grid20((rr / NG) % NG);
    fws[OFF_CN + 2] = grid20(rr % NG);
    fws[OFF_CN + 3] = (float)m;
  }
}

// ---------------- K4: fine scan — ec-split, DPP (r21 config) ---------------
__global__ __launch_bounds__(256) void k_fine(const float* __restrict__ fws,
                                              float2* __restrict__ partf) {
  __shared__ float4 row_ls[256];   // 4 KB
  __shared__ float4 row_sc[256];   // 4 KB
  int tid = threadIdx.x, lane = tid & 63, w = tid >> 6;
  float cn1 = fws[OFF_CN + 0];
  float cn2 = fws[OFF_CN + 1];
  float cn3 = fws[OFF_CN + 2];
  int m = (int)fws[OFF_CN + 3];

  int b = blockIdx.x;
  int cp = b >> 1, ec = b & 1;
  int j2 = cp / 15;
  int p3 = cp % 15;
  int j3A = 2 * p3;
  float n2 = finev(cn2, j2);
  float n3A = finev(cn3, j3A);
  float n3B = finev(cn3, j3A + 1);

  const float2* tab = reinterpret_cast<const float2*>(fws + OFF_TAB) + m * HALF;
  const float2* sc = reinterpret_cast<const float2*>(fws + OFF_SC);
  {
    int q = tid;                       // local pair [0,256)
    int gq = ec * 256 + q;             // global pair
    int e0 = 2 * gq, e1 = e0 + 1;
    float2 tb0 = tab[e0], tb1 = tab[e1];
    float2 s0 = sc[e0], s1 = sc[e1];
    float a20 = EXP2F(n2 * tb0.x), a21 = EXP2F(n2 * tb1.x);
    float4 ls;
    ls.x = LOG2F(a20 + EXP2F(n3A * tb0.y));
    ls.y = LOG2F(a21 + EXP2F(n3A * tb1.y));
    ls.z = LOG2F(a20 + EXP2F(n3B * tb0.y));
    ls.w = LOG2F(a21 + EXP2F(n3B * tb1.y));
    row_ls[q] = ls;
    row_sc[q] = make_float4(s0.x, s1.x, s0.y, s1.y);
  }
  __syncthreads();

  int npairs = (w < 3) ? 4 : 3;   // j1 counts 8,8,8,6
  for (int pp = 0; pp < npairs; ++pp) {
    int j1a = w * 8 + pp * 2;
    float r0s = -1.0f / finev(cn1, j1a);
    float r1s = -1.0f / finev(cn1, j1a + 1);
    f32x2 r0 = {r0s, r0s}, r1 = {r1s, r1s};
    f32x2 z = {0.0f, 0.0f};
    f32x2 aA0 = z, tA0 = z, aB0 = z, tB0 = z;
    f32x2 aA1 = z, tA1 = z, aB1 = z, tB1 = z;
#pragma unroll 4
    for (int it = 0; it < 4; ++it) {
      int q = lane + it * 64;
      float4 ls4 = row_ls[q];
      float4 sc4 = row_sc[q];
      f32x2 lsA = {ls4.x, ls4.y}, lsB = {ls4.z, ls4.w};
      f32x2 sx = {sc4.x, sc4.y}, sy = {sc4.z, sc4.w};
      f32x2 e, e2;
      e = pk_exp2(pk_mul(r0, lsA)); e2 = pk_mul(e, e);
      aA0 = pk_fma(e2, sx, aA0); tA0 = pk_fma(e, sy, tA0);
      e = pk_exp2(pk_mul(r0, lsB)); e2 = pk_mul(e, e);
      aB0 = pk_fma(e2, sx, aB0); tB0 = pk_fma(e, sy, tB0);
      e = pk_exp2(pk_mul(r1, lsA)); e2 = pk_mul(e, e);
      aA1 = pk_fma(e2, sx, aA1); tA1 = pk_fma(e, sy, tA1);
      e = pk_exp2(pk_mul(r1, lsB)); e2 = pk_mul(e, e);
      aB1 = pk_fma(e2, sx, aB1); tB1 = pk_fma(e, sy, tB1);
    }
    float aA0s = wave_sum63(aA0.x + aA0.y);
    float tA0s = wave_sum63(tA0.x + tA0.y);
    float aB0s = wave_sum63(aB0.x + aB0.y);
    float tB0s = wave_sum63(tB0.x + tB0.y);
    float aA1s = wave_sum63(aA1.x + aA1.y);
    float tA1s = wave_sum63(tA1.x + tA1.y);
    float aB1s = wave_sum63(aB1.x + aB1.y);
    float tB1s = wave_sum63(tB1.x + tB1.y);
    if (lane == 63) {
      int t0 = (j1a * NF + j2) * NF + j3A;   // fine flat index
      partf[2 * t0 + ec]       = make_float2(aA0s, tA0s);
      partf[2 * (t0 + 1) + ec] = make_float2(aB0s, tB0s);
      int t1 = t0 + NF * NF;
      partf[2 * t1 + ec]       = make_float2(aA1s, tA1s);
      partf[2 * (t1 + 1) + ec] = make_float2(aB1s, tB1s);
    }
  }
}

// ---------------- K5: fine finalize (combine halves, f64) + argmin st.1 ----
__global__ __launch_bounds__(256) void k_ffin(const float2* __restrict__ partf,
                                              const double* __restrict__ dstt,
                                              double* __restrict__ pv,
                                              int* __restrict__ pi) {
  int t = blockIdx.x * 256 + threadIdx.x;
  double best = 1e300; int bi = 0x7fffffff;
  if (t < NF * NF * NF) {
    float2 p0 = partf[2 * t];
    float2 p1 = partf[2 * t + 1];
    double sgg = (double)p0.x + (double)p1.x;
    double sgt = (double)p0.y + (double)p1.y;
    best = mse_from(2.0 * sgg, sgt, dstt[0]);
    bi = t;
  }
  __shared__ double sv[4];
  __shared__ int st[4];
  vt_block_merge(best, bi, sv, st);
  if (threadIdx.x == 0) { pv[blockIdx.x] = best; pi[blockIdx.x] = bi; }
}

// ---------------- K6: final fine argmin + emit -----------------------------
__global__ __launch_bounds__(256) void k_out(const float* __restrict__ fws,
                                             const double* __restrict__ pvf,
                                             const int* __restrict__ pif,
                                             float* __restrict__ out) {
  __shared__ double sv[4];
  __shared__ int st[4];
  double v = 1e300; int t = 0x7fffffff;
  for (int i = threadIdx.x; i < NBF; i += 256) {
    double ov = pvf[i]; int ot = pif[i];
    if (ov < v || (ov == v && ot < t)) { v = ov; t = ot; }
  }
  vt_block_merge(v, t, sv, st);
  if (threadIdx.x == 0) {
    float cn1 = fws[OFF_CN + 0];
    float cn2 = fws[OFF_CN + 1];
    float cn3 = fws[OFF_CN + 2];
    int m = (int)fws[OFF_CN + 3];
    int fi = t;
    int f1 = fi / (NF * NF);
    int fc = fi % (NF * NF);
    out[0] = (float)(m + 1);
    out[1] = finev(cn1, f1);
    out[2] = finev(cn2, fc / NF);
    out[3] = finev(cn3, fc % NF);
  }
}

extern "C" void kernel_launch(void* const* d_in, const int* in_sizes, int n_in,
                              void* d_out, int out_size, void* d_ws, size_t ws_size,
                              hipStream_t stream) {
  const float* x = (const float*)d_in[0];
  const int* freqp = (const int*)d_in[1];
  float* out = (float*)d_out;
  float* fws = (float*)d_ws;

  double* D0  = (double*)(fws + OFF_DWS);   // byte 90288, 8-aligned
  double* dstt = D0;                        // [1]
  double* bvc = D0 + 1;                     // NCC2 doubles
  double* pvf = bvc + NCC2;                 // NBF doubles
  int* btc = (int*)(pvf + NBF);             // NCC2 ints
  int* pif = btc + NCC2;                    // NBF ints
  float2* partf = (float2*)(pif + NBF + 1); // 27000*2 float2 (8B-aligned)

  hipLaunchKernelGGL(k_init,   dim3(41),   dim3(256), 0, stream, x, freqp, fws, dstt);
  hipLaunchKernelGGL(k_coarse, dim3(NCC2), dim3(256), 0, stream, fws, dstt, bvc, btc);
  hipLaunchKernelGGL(k_cmin,   dim3(1),    dim3(256), 0, stream, bvc, btc, fws);
  hipLaunchKernelGGL(k_fine,   dim3(NFB2), dim3(256), 0, stream, fws, partf);
  hipLaunchKernelGGL(k_ffin,   dim3(NBF),  dim3(256), 0, stream, partf, dstt, pvf, pif);
  hipLaunchKernelGGL(k_out,    dim3(1),    dim3(256), 0, stream, fws, pvf, pif, out);
}